// Round 12
// baseline (429.425 us; speedup 1.0000x reference)
//
#include <hip/hip_runtime.h>
#include <hip/hip_bf16.h>

constexpr int FDIM = 128;

typedef __attribute__((ext_vector_type(8))) short bf16x8;   // 8 bf16 = 4 VGPRs
typedef __attribute__((ext_vector_type(4))) float f32x4;
typedef __attribute__((ext_vector_type(2))) float f32x2;

static __device__ __forceinline__ ushort f2bf(float f){
    union { float f; unsigned u; } v; v.f = f;
    unsigned r = v.u + 0x7fffu + ((v.u >> 16) & 1u);   // RNE
    return (ushort)(r >> 16);
}
static __device__ __forceinline__ unsigned char f2fp8(float f){
    return (unsigned char)(__builtin_amdgcn_cvt_pk_fp8_f32(f, f, 0, false) & 0xff);
}
// real XCD id (0..7) — wave-uniform; used for L2 locality only (correctness never depends on it)
static __device__ __forceinline__ int get_xcc(){
    int x;
    asm volatile("s_getreg_b32 %0, hwreg(HW_REG_XCC_ID)" : "=s"(x));
    return x & 7;
}

// ---------------- pass 1 (fused): XCD-owned windowed degree+rank+compact | x cast | weight swizzle ----
// Degree workers: win = own XCC_ID; slices grabbed from per-window counters (work-stealing fallback
// guarantees full coverage whatever the block->XCD distribution). deg atomics stay in the owning
// XCD's L2 -> no cross-die line bounce. Records {src|dst<<16, rank} compacted per (win,slice) region.

__global__ __launch_bounds__(256) void k_pass1(
    const int* __restrict__ dst, const int* __restrict__ src,
    int* __restrict__ deg, int* __restrict__ wcnt, uint2* __restrict__ recs, int* __restrict__ counts,
    int E, int WINW, int ES, int SLICES, int gW,
    const float* __restrict__ xsrc, ushort* __restrict__ xb, unsigned char* __restrict__ x8, int nx, int gC,
    const float* __restrict__ W1_l, const float* __restrict__ W1_r,
    const float* __restrict__ Wl1,
    const float* __restrict__ W2_l, const float* __restrict__ W2_r,
    ushort* __restrict__ Wf1, ushort* __restrict__ Wfm, ushort* __restrict__ Wf2)
{
    const int b = (int)blockIdx.x;
    if (b < gW){
        __shared__ int task, lcnt;
        const int xcc = get_xcc();
        for (int wq = 0; wq < 8; wq++){
            const int win = (xcc + wq) & 7;
            const int lo = win * WINW, hi = lo + WINW;
            for (;;){
                if (threadIdx.x == 0){ task = atomicAdd(&wcnt[win], 1); lcnt = 0; }
                __syncthreads();
                const int s = task;
                if (s >= SLICES) break;                 // block-uniform
                const int e0 = s * ES, e1 = min(E, e0 + ES);
                uint2* myrec = recs + (size_t)(win*SLICES + s) * ES;
                for (int e = e0 + (int)threadIdx.x; e < e1; e += 256){
                    int d = dst[e];
                    if (d >= lo && d < hi){
                        int r   = atomicAdd(&deg[d], 1);   // XCD-local L2 atomic
                        int pos = atomicAdd(&lcnt, 1);     // LDS counter
                        myrec[pos] = make_uint2((unsigned)src[e] | ((unsigned)d << 16), (unsigned)r);
                    }
                }
                __syncthreads();
                if (threadIdx.x == 0) counts[win*SLICES + s] = lcnt;
                __syncthreads();
            }
        }
    } else if (b < gW + gC){
        int i4 = ((b - gW)*256 + threadIdx.x) * 4;
        if (i4 < nx){
            float4 v = *(const float4*)(xsrc + i4);
            ushort4 o; o.x=f2bf(v.x); o.y=f2bf(v.y); o.z=f2bf(v.z); o.w=f2bf(v.w);
            *(ushort4*)(xb + i4) = o;
            unsigned w = __builtin_amdgcn_cvt_pk_fp8_f32(v.x, v.y, 0, false);
            w = (unsigned)__builtin_amdgcn_cvt_pk_fp8_f32(v.z, v.w, (int)w, true);
            *(unsigned*)(x8 + i4) = w;
        }
    } else {
        // weight swizzle into MFMA fragment order:
        // Wf[((nt*8+kt)*64 + lane)*8 + j] = W[nt*16 + (lane&15)][kt*32 + (lane>>4)*8 + j]
        int i = (b - gW - gC)*256 + threadIdx.x;       // 320 blocks -> 81920 ushorts
        int f; ushort* dstp; int which;
        if (i < 32768){ f = i;          dstp = Wf1; which = 0; }
        else if (i < 65536){ f = i - 32768; dstp = Wfm; which = 1; }
        else { f = i - 65536; dstp = Wf2; which = 2; }
        int j    = f & 7;
        int lane = (f >> 3) & 63;
        int q    = f >> 9;
        int kt = q & 7, nt = q >> 3;
        int n = nt*16 + (lane & 15);
        int k = kt*32 + (lane >> 4)*8 + j;
        float v;
        if (which == 0)      v = (k < 128) ? W1_l[(size_t)n*128 + k] : W1_r[(size_t)n*128 + (k-128)];
        else if (which == 1) v = Wl1[(size_t)n*256 + k];
        else                 v = (k < 128) ? W2_l[(size_t)n*128 + k] : W2_r[(size_t)n*128 + (k-128)];
        dstp[f] = f2bf(v);
    }
}

__global__ __launch_bounds__(256) void k_scan1(const int* __restrict__ deg, int* __restrict__ partial,
                                               int* __restrict__ bsum, int N){
    __shared__ int s[256];
    int i = blockIdx.x*256 + threadIdx.x;
    int v = (i < N) ? deg[i] : 0;
    s[threadIdx.x] = v;
    __syncthreads();
    for (int ofs = 1; ofs < 256; ofs <<= 1){
        int add = (threadIdx.x >= ofs) ? s[threadIdx.x - ofs] : 0;
        __syncthreads();
        s[threadIdx.x] += add;
        __syncthreads();
    }
    if (i < N) partial[i] = s[threadIdx.x];
    if (threadIdx.x == 255) bsum[blockIdx.x] = s[255];
}

// fused scan2+scan3: every block redundantly scans the <=256 block sums in LDS, then applies.
__global__ __launch_bounds__(256) void k_scan23(const int* __restrict__ partial, const int* __restrict__ deg,
                                                const int* __restrict__ bsum, int* __restrict__ off,
                                                int N, int nb){
    __shared__ int s[256];
    __shared__ int excl;
    int t = threadIdx.x;
    int v = (t < nb) ? bsum[t] : 0;
    s[t] = v;
    __syncthreads();
    for (int ofs = 1; ofs < 256; ofs <<= 1){
        int add = (t >= ofs) ? s[t - ofs] : 0;
        __syncthreads();
        s[t] += add;
        __syncthreads();
    }
    if (t == 0) excl = (blockIdx.x == 0) ? 0 : s[blockIdx.x - 1];
    __syncthreads();
    int i = blockIdx.x*256 + t;
    if (i < N) off[i] = partial[i] - deg[i] + excl;
}

// ---------------- scatter records -> csr: XCD-owned windows via same stealing scheme ----------------
// csr window region (~400 KB) written only by blocks on the owning XCD -> L2-local.

__global__ __launch_bounds__(256) void k_scatter(const uint2* __restrict__ recs, const int* __restrict__ counts,
                                                 const int* __restrict__ off, int* __restrict__ csr,
                                                 int* __restrict__ wcnt2, int ES, int SLICES){
    __shared__ int task;
    const int xcc = get_xcc();
    for (int wq = 0; wq < 8; wq++){
        const int win = (xcc + wq) & 7;
        for (;;){
            if (threadIdx.x == 0) task = atomicAdd(&wcnt2[win], 1);
            __syncthreads();
            const int s = task;
            __syncthreads();
            if (s >= SLICES) break;                 // block-uniform
            const int rix = win*SLICES + s;
            const int cnt = counts[rix];
            const uint2* myrec = recs + (size_t)rix * ES;
            for (int i = (int)threadIdx.x; i < cnt; i += 256){
                uint2 rec = myrec[i];
                int d = (int)(rec.x >> 16);
                int sr = (int)(rec.x & 0xffffu);
                csr[off[d] + (int)rec.y] = sr;
            }
        }
    }
}

// ---------------- mean aggregation over fp8 features: one wave per node, 16 edges in flight ----------------

__global__ __launch_bounds__(256) void k_agg8(
    const unsigned char* __restrict__ feat8, const int* __restrict__ csr,
    const int* __restrict__ off, const int* __restrict__ deg,
    ushort* __restrict__ agg, int N)
{
    int node = (blockIdx.x*256 + threadIdx.x) >> 6;
    int lane = threadIdx.x & 63;
    if (node >= N) return;
    const int grp = lane >> 4;
    const int sub = lane & 15;        // cols [sub*8, sub*8+8)
    int o = off[node], d = deg[node];

    float a0=0.f,a1=0.f,a2=0.f,a3=0.f,a4=0.f,a5=0.f,a6=0.f,a7=0.f;

    auto accum = [&](uint2 r){
        f32x2 f;
        f = __builtin_amdgcn_cvt_pk_f32_fp8((int)r.x, false); a0 += f.x; a1 += f.y;
        f = __builtin_amdgcn_cvt_pk_f32_fp8((int)r.x, true);  a2 += f.x; a3 += f.y;
        f = __builtin_amdgcn_cvt_pk_f32_fp8((int)r.y, false); a4 += f.x; a5 += f.y;
        f = __builtin_amdgcn_cvt_pk_f32_fp8((int)r.y, true);  a6 += f.x; a7 += f.y;
    };

    for (int base = 0; base < d; base += 64){
        int cnt = min(64, d - base);
        int idx = (lane < cnt) ? csr[o + base + lane] : -1;
        int iters = (cnt + 3) >> 2;
        int j = 0;
        for (; j + 4 <= iters; j += 4){
            int s0 = __shfl(idx, (j+0)*4 + grp);
            int s1 = __shfl(idx, (j+1)*4 + grp);
            int s2 = __shfl(idx, (j+2)*4 + grp);
            int s3 = __shfl(idx, (j+3)*4 + grp);
            unsigned m0 = (s0 >= 0) ? 0xffffffffu : 0u;  int p0 = (s0 >= 0) ? s0 : 0;
            unsigned m1 = (s1 >= 0) ? 0xffffffffu : 0u;  int p1 = (s1 >= 0) ? s1 : 0;
            unsigned m2 = (s2 >= 0) ? 0xffffffffu : 0u;  int p2 = (s2 >= 0) ? s2 : 0;
            unsigned m3 = (s3 >= 0) ? 0xffffffffu : 0u;  int p3 = (s3 >= 0) ? s3 : 0;
            uint2 r0 = *(const uint2*)(feat8 + (size_t)p0*FDIM + sub*8);
            uint2 r1 = *(const uint2*)(feat8 + (size_t)p1*FDIM + sub*8);
            uint2 r2 = *(const uint2*)(feat8 + (size_t)p2*FDIM + sub*8);
            uint2 r3 = *(const uint2*)(feat8 + (size_t)p3*FDIM + sub*8);
            r0.x &= m0; r0.y &= m0;  r1.x &= m1; r1.y &= m1;   // fp8 0x00 == 0.0
            r2.x &= m2; r2.y &= m2;  r3.x &= m3; r3.y &= m3;
            accum(r0); accum(r1); accum(r2); accum(r3);
        }
        for (; j < iters; j++){
            int s = __shfl(idx, j*4 + grp);
            unsigned msk = (s >= 0) ? 0xffffffffu : 0u;
            int sr = (s >= 0) ? s : 0;
            uint2 raw = *(const uint2*)(feat8 + (size_t)sr*FDIM + sub*8);
            raw.x &= msk; raw.y &= msk;
            accum(raw);
        }
    }

    a0 += __shfl_xor(a0,16); a1 += __shfl_xor(a1,16); a2 += __shfl_xor(a2,16); a3 += __shfl_xor(a3,16);
    a4 += __shfl_xor(a4,16); a5 += __shfl_xor(a5,16); a6 += __shfl_xor(a6,16); a7 += __shfl_xor(a7,16);
    a0 += __shfl_xor(a0,32); a1 += __shfl_xor(a1,32); a2 += __shfl_xor(a2,32); a3 += __shfl_xor(a3,32);
    a4 += __shfl_xor(a4,32); a5 += __shfl_xor(a5,32); a6 += __shfl_xor(a6,32); a7 += __shfl_xor(a7,32);

    if (grp == 0){
        float inv = 1.f / (float)(d > 1 ? d : 1);
        uint4 r;
        r.x = (unsigned)f2bf(a0*inv) | ((unsigned)f2bf(a1*inv) << 16);
        r.y = (unsigned)f2bf(a2*inv) | ((unsigned)f2bf(a3*inv) << 16);
        r.z = (unsigned)f2bf(a4*inv) | ((unsigned)f2bf(a5*inv) << 16);
        r.w = (unsigned)f2bf(a6*inv) | ((unsigned)f2bf(a7*inv) << 16);
        *(uint4*)(agg + (size_t)node*FDIM + sub*8) = r;
    }
}

// ---------------- LDS-weight linear (weights staged once/block, conflict-free ds_read_b128) ----------------

template<int NT, bool NORM, bool RELU, bool OUTF32, bool FP8OUT>
__global__ __launch_bounds__(256) void k_lin(
    const ushort* __restrict__ A1, const ushort* __restrict__ A2,
    const ushort* __restrict__ Wf, const float* __restrict__ bias,
    void* __restrict__ outv, unsigned char* __restrict__ out8, int N, int TILES)
{
    __shared__ __align__(16) ushort WS[NT*8*64*8];   // NT*8 KB
    {
        const uint4* wsrc = (const uint4*)Wf;
        uint4* wdst = (uint4*)WS;
        for (int i = threadIdx.x; i < NT*512; i += 256) wdst[i] = wsrc[i];
    }
    __syncthreads();

    const int wave = threadIdx.x >> 6, lane = threadIdx.x & 63;
    const int m = lane & 15, quad = lane >> 4;
    const ushort* WSl = WS + lane*8;    // frag (nt,kt) at WSl + (nt*8+kt)*512

    const int g  = blockIdx.x*4 + wave;          // 0..2047
    const int t0 = g, t1 = g + 2048;
    const bool has2 = (t1 < TILES);

    bf16x8 af0[8], af1[8];
    {
        int r0 = min(t0*16 + m, N-1);
        const ushort* p1 = A1 + (size_t)r0*FDIM + quad*8;
        const ushort* p2 = A2 + (size_t)r0*FDIM + quad*8;
        #pragma unroll
        for (int c = 0; c < 4; c++){
            af0[c]   = *(const bf16x8*)(p1 + c*32);
            af0[4+c] = *(const bf16x8*)(p2 + c*32);
        }
    }
    if (has2){
        int r1 = min(t1*16 + m, N-1);
        const ushort* p1 = A1 + (size_t)r1*FDIM + quad*8;
        const ushort* p2 = A2 + (size_t)r1*FDIM + quad*8;
        #pragma unroll
        for (int c = 0; c < 4; c++){
            af1[c]   = *(const bf16x8*)(p1 + c*32);
            af1[4+c] = *(const bf16x8*)(p2 + c*32);
        }
    }

    f32x4 acc0[NT], acc1[NT];
    #pragma unroll
    for (int nt = 0; nt < NT; nt++){ acc0[nt] = f32x4{0.f,0.f,0.f,0.f}; acc1[nt] = f32x4{0.f,0.f,0.f,0.f}; }

    if (has2){
        #pragma unroll
        for (int kt = 0; kt < 8; kt++)
            #pragma unroll
            for (int nt = 0; nt < NT; nt++){
                bf16x8 bfr = *(const bf16x8*)(WSl + (nt*8+kt)*512);
                acc0[nt] = __builtin_amdgcn_mfma_f32_16x16x32_bf16(af0[kt], bfr, acc0[nt], 0, 0, 0);
                acc1[nt] = __builtin_amdgcn_mfma_f32_16x16x32_bf16(af1[kt], bfr, acc1[nt], 0, 0, 0);
            }
    } else {
        #pragma unroll
        for (int kt = 0; kt < 8; kt++)
            #pragma unroll
            for (int nt = 0; nt < NT; nt++){
                bf16x8 bfr = *(const bf16x8*)(WSl + (nt*8+kt)*512);
                acc0[nt] = __builtin_amdgcn_mfma_f32_16x16x32_bf16(af0[kt], bfr, acc0[nt], 0, 0, 0);
            }
    }

    auto epi = [&](int t, f32x4* acc){
        #pragma unroll
        for (int nt = 0; nt < NT; nt++){
            float b = bias[nt*16 + m];
            acc[nt][0]+=b; acc[nt][1]+=b; acc[nt][2]+=b; acc[nt][3]+=b;
        }
        if (NORM){
            #pragma unroll
            for (int reg = 0; reg < 4; reg++){
                float ss = 0.f;
                #pragma unroll
                for (int nt = 0; nt < NT; nt++) ss += acc[nt][reg]*acc[nt][reg];
                ss += __shfl_xor(ss,1); ss += __shfl_xor(ss,2); ss += __shfl_xor(ss,4); ss += __shfl_xor(ss,8);
                float invn = 1.f / fmaxf(sqrtf(ss), 1e-12f);
                #pragma unroll
                for (int nt = 0; nt < NT; nt++) acc[nt][reg] *= invn;
            }
        }
        if (RELU){
            #pragma unroll
            for (int nt = 0; nt < NT; nt++){
                acc[nt][0]=fmaxf(acc[nt][0],0.f); acc[nt][1]=fmaxf(acc[nt][1],0.f);
                acc[nt][2]=fmaxf(acc[nt][2],0.f); acc[nt][3]=fmaxf(acc[nt][3],0.f);
            }
        }
        #pragma unroll
        for (int reg = 0; reg < 4; reg++){
            int row = t*16 + quad*4 + reg;
            if (row < N){
                if (OUTF32){
                    float* o = (float*)outv + (size_t)row*(NT*16) + m;
                    #pragma unroll
                    for (int nt = 0; nt < NT; nt++) o[nt*16] = acc[nt][reg];
                } else {
                    ushort* o = (ushort*)outv + (size_t)row*(NT*16) + m;
                    #pragma unroll
                    for (int nt = 0; nt < NT; nt++) o[nt*16] = f2bf(acc[nt][reg]);
                    if (FP8OUT){
                        unsigned char* o8 = out8 + (size_t)row*(NT*16) + m;
                        #pragma unroll
                        for (int nt = 0; nt < NT; nt++) o8[nt*16] = f2fp8(acc[nt][reg]);
                    }
                }
            }
        }
    };
    epi(t0, acc0);
    if (has2) epi(t1, acc1);
}

// ---------------- launch ----------------

extern "C" void kernel_launch(void* const* d_in, const int* in_sizes, int n_in,
                              void* d_out, int out_size, void* d_ws, size_t ws_size,
                              hipStream_t stream)
{
    const float* x    = (const float*)d_in[0];
    const int*   ei   = (const int*)  d_in[1];
    const float* W1_l = (const float*)d_in[2];
    const float* b1_l = (const float*)d_in[3];
    const float* W1_r = (const float*)d_in[4];
    const float* Wl1  = (const float*)d_in[5];
    const float* bl1  = (const float*)d_in[6];
    const float* W2_l = (const float*)d_in[7];
    const float* b2_l = (const float*)d_in[8];
    const float* W2_r = (const float*)d_in[9];
    float* out = (float*)d_out;

    const int N = in_sizes[0] / FDIM;   // 50000
    const int E = in_sizes[1] / 2;      // 800000

    const int* src = ei;
    const int* dst = ei + E;

    char* p = (char*)d_ws;
    auto carve = [&](size_t bytes) -> void* {
        void* r = (void*)p;
        p += (bytes + 255) & ~(size_t)255;
        return r;
    };
    const int SLICES = 128;
    const int gW     = 1024;                          // degree worker blocks (self-assigning)
    const int ES     = (E + SLICES - 1) / SLICES;     // 6250 edges/slice

    int*           zero0   = (int*)   carve(((size_t)N + 128) * 4);  // deg + wcnt + wcnt2 (one memset)
    int*           deg     = zero0;
    int*           wcnt    = zero0 + N;          // 8 counters (64B-padded region)
    int*           wcnt2   = zero0 + N + 64;     // 8 counters
    int*           partial = (int*)   carve((size_t)N * 4);
    int*           bsum    = (int*)   carve(256 * 4);
    int*           off     = (int*)   carve((size_t)N * 4);
    int*           csr     = (int*)   carve((size_t)E * 4);
    uint2*         recs    = (uint2*) carve((size_t)8 * SLICES * ES * 8);
    int*           counts  = (int*)   carve((size_t)8 * SLICES * 4);
    ushort*        xb      = (ushort*)carve((size_t)N * FDIM * 2);
    ushort*        h1b     = (ushort*)carve((size_t)N * FDIM * 2);
    ushort*        hb      = (ushort*)carve((size_t)N * FDIM * 2);
    ushort*        aggb    = (ushort*)carve((size_t)N * FDIM * 2);
    unsigned char* x8      = (unsigned char*)carve((size_t)N * FDIM);
    unsigned char* h8      = (unsigned char*)carve((size_t)N * FDIM);
    ushort*        Wf1     = (ushort*)carve((size_t)32768 * 2);
    ushort*        Wfm     = (ushort*)carve((size_t)32768 * 2);
    ushort*        Wf2     = (ushort*)carve((size_t)16384 * 2);

    hipMemsetAsync(zero0, 0, ((size_t)N + 128) * 4, stream);

    const int gN    = (N + 255) / 256;
    const int gAgg  = (N + 3) / 4;                    // 4 waves/block, 1 node/wave
    const int gCast = (N * FDIM / 4 + 255) / 256;
    const int WINW  = (N + 7) / 8;                    // 8 windows
    const int TILES = (N + 15) / 16;                  // 3125
    const int gLin  = 512;                            // 2048 wave slots, 2 tiles/wave

    // pass 1: XCD-owned degree+rank+compact | x->bf16+fp8 | weight swizzle (fused)
    k_pass1<<<gW + gCast + 320, 256, 0, stream>>>(dst, src, deg, wcnt, recs, counts,
                                                  E, WINW, ES, SLICES, gW,
                                                  x, xb, x8, N*FDIM, gCast,
                                                  W1_l, W1_r, Wl1, W2_l, W2_r, Wf1, Wfm, Wf2);
    k_scan1 <<<gN, 256, 0, stream>>>(deg, partial, bsum, N);
    k_scan23<<<gN, 256, 0, stream>>>(partial, deg, bsum, off, N, gN);
    k_scatter<<<1024, 256, 0, stream>>>(recs, counts, off, csr, wcnt2, ES, SLICES);

    // layer 1: h1 = relu(norm([agg(x)|x] @ W1^T + b1))
    k_agg8<<<gAgg, 256, 0, stream>>>(x8, csr, off, deg, aggb, N);
    k_lin<8, true,  true,  false, false><<<gLin, 256, 0, stream>>>(aggb, xb, Wf1, b1_l, h1b, nullptr, N, TILES);

    // mid: h = relu([x|h1] @ Wl1^T + bl1)   (also emits fp8 copy for layer-2 gather)
    k_lin<8, false, true,  false, true ><<<gLin, 256, 0, stream>>>(xb, h1b, Wfm, bl1, hb, h8, N, TILES);

    // layer 2: out = norm([agg(h)|h] @ W2^T + b2)  (fp32 out)
    k_agg8<<<gAgg, 256, 0, stream>>>(h8, csr, off, deg, aggb, N);
    k_lin<4, true,  false, true,  false><<<gLin, 256, 0, stream>>>(aggb, hb, Wf2, b2_l, out, nullptr, N, TILES);
}

// Round 13
// 233.856 us; speedup vs baseline: 1.8363x; 1.8363x over previous
//
#include <hip/hip_runtime.h>
#include <hip/hip_bf16.h>

constexpr int FDIM = 128;

typedef __attribute__((ext_vector_type(8))) short bf16x8;   // 8 bf16 = 4 VGPRs
typedef __attribute__((ext_vector_type(4))) float f32x4;
typedef __attribute__((ext_vector_type(2))) float f32x2;

static __device__ __forceinline__ ushort f2bf(float f){
    union { float f; unsigned u; } v; v.f = f;
    unsigned r = v.u + 0x7fffu + ((v.u >> 16) & 1u);   // RNE
    return (ushort)(r >> 16);
}
static __device__ __forceinline__ unsigned char f2fp8(float f){
    return (unsigned char)(__builtin_amdgcn_cvt_pk_fp8_f32(f, f, 0, false) & 0xff);
}

// ---------------- pass 1 (fused): single-pass degree+rank+bin | x cast | weight swizzle ----------------
// Worker blocks: one slice of ~782 edges each, dst/src read ONCE (vs 8x in the per-window scheme).
// Window w = d>>13 (shift; 7 windows cover N=50000). deg atomic is random/device-wide (R10/R12
// established windowing/XCD-pinning it doesn't help). Records {src|dst<<16, rank} binned into
// per-(slice,window) regions via LDS counters; scatter gets window confinement for csr locality.

__global__ __launch_bounds__(256) void k_pass1(
    const int* __restrict__ dst, const int* __restrict__ src,
    int* __restrict__ deg, uint2* __restrict__ recs, int* __restrict__ counts,
    int E, int ES, int gW,
    const float* __restrict__ xsrc, ushort* __restrict__ xb, unsigned char* __restrict__ x8, int nx, int gC,
    const float* __restrict__ W1_l, const float* __restrict__ W1_r,
    const float* __restrict__ Wl1,
    const float* __restrict__ W2_l, const float* __restrict__ W2_r,
    ushort* __restrict__ Wf1, ushort* __restrict__ Wfm, ushort* __restrict__ Wf2)
{
    const int b = (int)blockIdx.x;
    if (b < gW){
        __shared__ int bcnt[8];
        if (threadIdx.x < 8) bcnt[threadIdx.x] = 0;
        __syncthreads();
        const int e0 = b * ES, e1 = min(E, e0 + ES);
        for (int e = e0 + (int)threadIdx.x; e < e1; e += 256){
            int d  = dst[e];
            int sr = src[e];
            int w  = d >> 13;                          // 0..6 for N=50000
            int r   = atomicAdd(&deg[d], 1);           // rank
            int pos = atomicAdd(&bcnt[w], 1);          // LDS bin counter
            recs[(size_t)(b*8 + w)*ES + pos] = make_uint2((unsigned)sr | ((unsigned)d << 16), (unsigned)r);
        }
        __syncthreads();
        if (threadIdx.x < 8) counts[b*8 + (int)threadIdx.x] = bcnt[threadIdx.x];
    } else if (b < gW + gC){
        int i4 = ((b - gW)*256 + threadIdx.x) * 4;
        if (i4 < nx){
            float4 v = *(const float4*)(xsrc + i4);
            ushort4 o; o.x=f2bf(v.x); o.y=f2bf(v.y); o.z=f2bf(v.z); o.w=f2bf(v.w);
            *(ushort4*)(xb + i4) = o;
            unsigned w = __builtin_amdgcn_cvt_pk_fp8_f32(v.x, v.y, 0, false);
            w = (unsigned)__builtin_amdgcn_cvt_pk_fp8_f32(v.z, v.w, (int)w, true);
            *(unsigned*)(x8 + i4) = w;
        }
    } else {
        // weight swizzle into MFMA fragment order:
        // Wf[((nt*8+kt)*64 + lane)*8 + j] = W[nt*16 + (lane&15)][kt*32 + (lane>>4)*8 + j]
        int i = (b - gW - gC)*256 + threadIdx.x;       // 320 blocks -> 81920 ushorts
        int f; ushort* dstp; int which;
        if (i < 32768){ f = i;          dstp = Wf1; which = 0; }
        else if (i < 65536){ f = i - 32768; dstp = Wfm; which = 1; }
        else { f = i - 65536; dstp = Wf2; which = 2; }
        int j    = f & 7;
        int lane = (f >> 3) & 63;
        int q    = f >> 9;
        int kt = q & 7, nt = q >> 3;
        int n = nt*16 + (lane & 15);
        int k = kt*32 + (lane >> 4)*8 + j;
        float v;
        if (which == 0)      v = (k < 128) ? W1_l[(size_t)n*128 + k] : W1_r[(size_t)n*128 + (k-128)];
        else if (which == 1) v = Wl1[(size_t)n*256 + k];
        else                 v = (k < 128) ? W2_l[(size_t)n*128 + k] : W2_r[(size_t)n*128 + (k-128)];
        dstp[f] = f2bf(v);
    }
}

__global__ __launch_bounds__(256) void k_scan1(const int* __restrict__ deg, int* __restrict__ partial,
                                               int* __restrict__ bsum, int N){
    __shared__ int s[256];
    int i = blockIdx.x*256 + threadIdx.x;
    int v = (i < N) ? deg[i] : 0;
    s[threadIdx.x] = v;
    __syncthreads();
    for (int ofs = 1; ofs < 256; ofs <<= 1){
        int add = (threadIdx.x >= ofs) ? s[threadIdx.x - ofs] : 0;
        __syncthreads();
        s[threadIdx.x] += add;
        __syncthreads();
    }
    if (i < N) partial[i] = s[threadIdx.x];
    if (threadIdx.x == 255) bsum[blockIdx.x] = s[255];
}

// fused scan2+scan3: every block redundantly scans the <=256 block sums in LDS, then applies.
__global__ __launch_bounds__(256) void k_scan23(const int* __restrict__ partial, const int* __restrict__ deg,
                                                const int* __restrict__ bsum, int* __restrict__ off,
                                                int N, int nb){
    __shared__ int s[256];
    __shared__ int excl;
    int t = threadIdx.x;
    int v = (t < nb) ? bsum[t] : 0;
    s[t] = v;
    __syncthreads();
    for (int ofs = 1; ofs < 256; ofs <<= 1){
        int add = (t >= ofs) ? s[t - ofs] : 0;
        __syncthreads();
        s[t] += add;
        __syncthreads();
    }
    if (t == 0) excl = (blockIdx.x == 0) ? 0 : s[blockIdx.x - 1];
    __syncthreads();
    int i = blockIdx.x*256 + t;
    if (i < N) off[i] = partial[i] - deg[i] + excl;
}

// ---------------- scatter records -> csr: window-confined via win = b&7 (proven R11 pattern) ----------------

__global__ __launch_bounds__(256) void k_scatter(const uint2* __restrict__ recs, const int* __restrict__ counts,
                                                 const int* __restrict__ off, int* __restrict__ csr,
                                                 int ES, int SLICES){
    const int b = (int)blockIdx.x;           // grid = SLICES*8
    const int win = b & 7, slice = b >> 3;
    const int rix = slice*8 + win;
    const int cnt = counts[rix];
    const uint2* myrec = recs + (size_t)rix * ES;
    for (int i = (int)threadIdx.x; i < cnt; i += 256){
        uint2 rec = myrec[i];
        int d  = (int)(rec.x >> 16);
        int sr = (int)(rec.x & 0xffffu);
        csr[off[d] + (int)rec.y] = sr;
    }
}

// ---------------- mean aggregation over fp8 features: one wave per node, 16 edges in flight ----------------

__global__ __launch_bounds__(256) void k_agg8(
    const unsigned char* __restrict__ feat8, const int* __restrict__ csr,
    const int* __restrict__ off, const int* __restrict__ deg,
    ushort* __restrict__ agg, int N)
{
    int node = (blockIdx.x*256 + threadIdx.x) >> 6;
    int lane = threadIdx.x & 63;
    if (node >= N) return;
    const int grp = lane >> 4;
    const int sub = lane & 15;        // cols [sub*8, sub*8+8)
    int o = off[node], d = deg[node];

    float a0=0.f,a1=0.f,a2=0.f,a3=0.f,a4=0.f,a5=0.f,a6=0.f,a7=0.f;

    auto accum = [&](uint2 r){
        f32x2 f;
        f = __builtin_amdgcn_cvt_pk_f32_fp8((int)r.x, false); a0 += f.x; a1 += f.y;
        f = __builtin_amdgcn_cvt_pk_f32_fp8((int)r.x, true);  a2 += f.x; a3 += f.y;
        f = __builtin_amdgcn_cvt_pk_f32_fp8((int)r.y, false); a4 += f.x; a5 += f.y;
        f = __builtin_amdgcn_cvt_pk_f32_fp8((int)r.y, true);  a6 += f.x; a7 += f.y;
    };

    for (int base = 0; base < d; base += 64){
        int cnt = min(64, d - base);
        int idx = (lane < cnt) ? csr[o + base + lane] : -1;
        int iters = (cnt + 3) >> 2;
        int j = 0;
        for (; j + 4 <= iters; j += 4){
            int s0 = __shfl(idx, (j+0)*4 + grp);
            int s1 = __shfl(idx, (j+1)*4 + grp);
            int s2 = __shfl(idx, (j+2)*4 + grp);
            int s3 = __shfl(idx, (j+3)*4 + grp);
            unsigned m0 = (s0 >= 0) ? 0xffffffffu : 0u;  int p0 = (s0 >= 0) ? s0 : 0;
            unsigned m1 = (s1 >= 0) ? 0xffffffffu : 0u;  int p1 = (s1 >= 0) ? s1 : 0;
            unsigned m2 = (s2 >= 0) ? 0xffffffffu : 0u;  int p2 = (s2 >= 0) ? s2 : 0;
            unsigned m3 = (s3 >= 0) ? 0xffffffffu : 0u;  int p3 = (s3 >= 0) ? s3 : 0;
            uint2 r0 = *(const uint2*)(feat8 + (size_t)p0*FDIM + sub*8);
            uint2 r1 = *(const uint2*)(feat8 + (size_t)p1*FDIM + sub*8);
            uint2 r2 = *(const uint2*)(feat8 + (size_t)p2*FDIM + sub*8);
            uint2 r3 = *(const uint2*)(feat8 + (size_t)p3*FDIM + sub*8);
            r0.x &= m0; r0.y &= m0;  r1.x &= m1; r1.y &= m1;   // fp8 0x00 == 0.0
            r2.x &= m2; r2.y &= m2;  r3.x &= m3; r3.y &= m3;
            accum(r0); accum(r1); accum(r2); accum(r3);
        }
        for (; j < iters; j++){
            int s = __shfl(idx, j*4 + grp);
            unsigned msk = (s >= 0) ? 0xffffffffu : 0u;
            int sr = (s >= 0) ? s : 0;
            uint2 raw = *(const uint2*)(feat8 + (size_t)sr*FDIM + sub*8);
            raw.x &= msk; raw.y &= msk;
            accum(raw);
        }
    }

    a0 += __shfl_xor(a0,16); a1 += __shfl_xor(a1,16); a2 += __shfl_xor(a2,16); a3 += __shfl_xor(a3,16);
    a4 += __shfl_xor(a4,16); a5 += __shfl_xor(a5,16); a6 += __shfl_xor(a6,16); a7 += __shfl_xor(a7,16);
    a0 += __shfl_xor(a0,32); a1 += __shfl_xor(a1,32); a2 += __shfl_xor(a2,32); a3 += __shfl_xor(a3,32);
    a4 += __shfl_xor(a4,32); a5 += __shfl_xor(a5,32); a6 += __shfl_xor(a6,32); a7 += __shfl_xor(a7,32);

    if (grp == 0){
        float inv = 1.f / (float)(d > 1 ? d : 1);
        uint4 r;
        r.x = (unsigned)f2bf(a0*inv) | ((unsigned)f2bf(a1*inv) << 16);
        r.y = (unsigned)f2bf(a2*inv) | ((unsigned)f2bf(a3*inv) << 16);
        r.z = (unsigned)f2bf(a4*inv) | ((unsigned)f2bf(a5*inv) << 16);
        r.w = (unsigned)f2bf(a6*inv) | ((unsigned)f2bf(a7*inv) << 16);
        *(uint4*)(agg + (size_t)node*FDIM + sub*8) = r;
    }
}

// ---------------- LDS-weight linear (weights staged once/block, conflict-free ds_read_b128) ----------------

template<int NT, bool NORM, bool RELU, bool OUTF32, bool FP8OUT>
__global__ __launch_bounds__(256) void k_lin(
    const ushort* __restrict__ A1, const ushort* __restrict__ A2,
    const ushort* __restrict__ Wf, const float* __restrict__ bias,
    void* __restrict__ outv, unsigned char* __restrict__ out8, int N, int TILES)
{
    __shared__ __align__(16) ushort WS[NT*8*64*8];   // NT*8 KB
    {
        const uint4* wsrc = (const uint4*)Wf;
        uint4* wdst = (uint4*)WS;
        for (int i = threadIdx.x; i < NT*512; i += 256) wdst[i] = wsrc[i];
    }
    __syncthreads();

    const int wave = threadIdx.x >> 6, lane = threadIdx.x & 63;
    const int m = lane & 15, quad = lane >> 4;
    const ushort* WSl = WS + lane*8;    // frag (nt,kt) at WSl + (nt*8+kt)*512

    const int g  = blockIdx.x*4 + wave;          // 0..2047
    const int t0 = g, t1 = g + 2048;
    const bool has2 = (t1 < TILES);

    bf16x8 af0[8], af1[8];
    {
        int r0 = min(t0*16 + m, N-1);
        const ushort* p1 = A1 + (size_t)r0*FDIM + quad*8;
        const ushort* p2 = A2 + (size_t)r0*FDIM + quad*8;
        #pragma unroll
        for (int c = 0; c < 4; c++){
            af0[c]   = *(const bf16x8*)(p1 + c*32);
            af0[4+c] = *(const bf16x8*)(p2 + c*32);
        }
    }
    if (has2){
        int r1 = min(t1*16 + m, N-1);
        const ushort* p1 = A1 + (size_t)r1*FDIM + quad*8;
        const ushort* p2 = A2 + (size_t)r1*FDIM + quad*8;
        #pragma unroll
        for (int c = 0; c < 4; c++){
            af1[c]   = *(const bf16x8*)(p1 + c*32);
            af1[4+c] = *(const bf16x8*)(p2 + c*32);
        }
    }

    f32x4 acc0[NT], acc1[NT];
    #pragma unroll
    for (int nt = 0; nt < NT; nt++){ acc0[nt] = f32x4{0.f,0.f,0.f,0.f}; acc1[nt] = f32x4{0.f,0.f,0.f,0.f}; }

    if (has2){
        #pragma unroll
        for (int kt = 0; kt < 8; kt++)
            #pragma unroll
            for (int nt = 0; nt < NT; nt++){
                bf16x8 bfr = *(const bf16x8*)(WSl + (nt*8+kt)*512);
                acc0[nt] = __builtin_amdgcn_mfma_f32_16x16x32_bf16(af0[kt], bfr, acc0[nt], 0, 0, 0);
                acc1[nt] = __builtin_amdgcn_mfma_f32_16x16x32_bf16(af1[kt], bfr, acc1[nt], 0, 0, 0);
            }
    } else {
        #pragma unroll
        for (int kt = 0; kt < 8; kt++)
            #pragma unroll
            for (int nt = 0; nt < NT; nt++){
                bf16x8 bfr = *(const bf16x8*)(WSl + (nt*8+kt)*512);
                acc0[nt] = __builtin_amdgcn_mfma_f32_16x16x32_bf16(af0[kt], bfr, acc0[nt], 0, 0, 0);
            }
    }

    auto epi = [&](int t, f32x4* acc){
        #pragma unroll
        for (int nt = 0; nt < NT; nt++){
            float b = bias[nt*16 + m];
            acc[nt][0]+=b; acc[nt][1]+=b; acc[nt][2]+=b; acc[nt][3]+=b;
        }
        if (NORM){
            #pragma unroll
            for (int reg = 0; reg < 4; reg++){
                float ss = 0.f;
                #pragma unroll
                for (int nt = 0; nt < NT; nt++) ss += acc[nt][reg]*acc[nt][reg];
                ss += __shfl_xor(ss,1); ss += __shfl_xor(ss,2); ss += __shfl_xor(ss,4); ss += __shfl_xor(ss,8);
                float invn = 1.f / fmaxf(sqrtf(ss), 1e-12f);
                #pragma unroll
                for (int nt = 0; nt < NT; nt++) acc[nt][reg] *= invn;
            }
        }
        if (RELU){
            #pragma unroll
            for (int nt = 0; nt < NT; nt++){
                acc[nt][0]=fmaxf(acc[nt][0],0.f); acc[nt][1]=fmaxf(acc[nt][1],0.f);
                acc[nt][2]=fmaxf(acc[nt][2],0.f); acc[nt][3]=fmaxf(acc[nt][3],0.f);
            }
        }
        #pragma unroll
        for (int reg = 0; reg < 4; reg++){
            int row = t*16 + quad*4 + reg;
            if (row < N){
                if (OUTF32){
                    float* o = (float*)outv + (size_t)row*(NT*16) + m;
                    #pragma unroll
                    for (int nt = 0; nt < NT; nt++) o[nt*16] = acc[nt][reg];
                } else {
                    ushort* o = (ushort*)outv + (size_t)row*(NT*16) + m;
                    #pragma unroll
                    for (int nt = 0; nt < NT; nt++) o[nt*16] = f2bf(acc[nt][reg]);
                    if (FP8OUT){
                        unsigned char* o8 = out8 + (size_t)row*(NT*16) + m;
                        #pragma unroll
                        for (int nt = 0; nt < NT; nt++) o8[nt*16] = f2fp8(acc[nt][reg]);
                    }
                }
            }
        }
    };
    epi(t0, acc0);
    if (has2) epi(t1, acc1);
}

// ---------------- launch ----------------

extern "C" void kernel_launch(void* const* d_in, const int* in_sizes, int n_in,
                              void* d_out, int out_size, void* d_ws, size_t ws_size,
                              hipStream_t stream)
{
    const float* x    = (const float*)d_in[0];
    const int*   ei   = (const int*)  d_in[1];
    const float* W1_l = (const float*)d_in[2];
    const float* b1_l = (const float*)d_in[3];
    const float* W1_r = (const float*)d_in[4];
    const float* Wl1  = (const float*)d_in[5];
    const float* bl1  = (const float*)d_in[6];
    const float* W2_l = (const float*)d_in[7];
    const float* b2_l = (const float*)d_in[8];
    const float* W2_r = (const float*)d_in[9];
    float* out = (float*)d_out;

    const int N = in_sizes[0] / FDIM;   // 50000
    const int E = in_sizes[1] / 2;      // 800000

    const int* src = ei;
    const int* dst = ei + E;

    char* p = (char*)d_ws;
    auto carve = [&](size_t bytes) -> void* {
        void* r = (void*)p;
        p += (bytes + 255) & ~(size_t)255;
        return r;
    };
    const int SLICES = 1024;
    const int gW     = SLICES;                        // pass-1 worker blocks (1 slice each)
    const int ES     = (E + SLICES - 1) / SLICES;     // 782 edges/slice

    int*           deg     = (int*)   carve((size_t)N * 4);
    int*           partial = (int*)   carve((size_t)N * 4);
    int*           bsum    = (int*)   carve(256 * 4);
    int*           off     = (int*)   carve((size_t)N * 4);
    int*           csr     = (int*)   carve((size_t)E * 4);
    uint2*         recs    = (uint2*) carve((size_t)SLICES * 8 * ES * 8);   // ~51 MB
    int*           counts  = (int*)   carve((size_t)SLICES * 8 * 4);
    ushort*        xb      = (ushort*)carve((size_t)N * FDIM * 2);
    ushort*        h1b     = (ushort*)carve((size_t)N * FDIM * 2);
    ushort*        hb      = (ushort*)carve((size_t)N * FDIM * 2);
    ushort*        aggb    = (ushort*)carve((size_t)N * FDIM * 2);
    unsigned char* x8      = (unsigned char*)carve((size_t)N * FDIM);
    unsigned char* h8      = (unsigned char*)carve((size_t)N * FDIM);
    ushort*        Wf1     = (ushort*)carve((size_t)32768 * 2);
    ushort*        Wfm     = (ushort*)carve((size_t)32768 * 2);
    ushort*        Wf2     = (ushort*)carve((size_t)16384 * 2);

    hipMemsetAsync(deg, 0, (size_t)N * 4, stream);

    const int gN    = (N + 255) / 256;
    const int gAgg  = (N + 3) / 4;                    // 4 waves/block, 1 node/wave
    const int gCast = (N * FDIM / 4 + 255) / 256;
    const int TILES = (N + 15) / 16;                  // 3125
    const int gLin  = 512;                            // 2048 wave slots, 2 tiles/wave

    // pass 1: single-pass degree+rank+bin | x->bf16+fp8 | weight swizzle (fused)
    k_pass1<<<gW + gCast + 320, 256, 0, stream>>>(dst, src, deg, recs, counts, E, ES, gW,
                                                  x, xb, x8, N*FDIM, gCast,
                                                  W1_l, W1_r, Wl1, W2_l, W2_r, Wf1, Wfm, Wf2);
    k_scan1 <<<gN, 256, 0, stream>>>(deg, partial, bsum, N);
    k_scan23<<<gN, 256, 0, stream>>>(partial, deg, bsum, off, N, gN);
    k_scatter<<<SLICES*8, 256, 0, stream>>>(recs, counts, off, csr, ES, SLICES);

    // layer 1: h1 = relu(norm([agg(x)|x] @ W1^T + b1))
    k_agg8<<<gAgg, 256, 0, stream>>>(x8, csr, off, deg, aggb, N);
    k_lin<8, true,  true,  false, false><<<gLin, 256, 0, stream>>>(aggb, xb, Wf1, b1_l, h1b, nullptr, N, TILES);

    // mid: h = relu([x|h1] @ Wl1^T + bl1)   (also emits fp8 copy for layer-2 gather)
    k_lin<8, false, true,  false, true ><<<gLin, 256, 0, stream>>>(xb, h1b, Wfm, bl1, hb, h8, N, TILES);

    // layer 2: out = norm([agg(h)|h] @ W2^T + b2)  (fp32 out)
    k_agg8<<<gAgg, 256, 0, stream>>>(h8, csr, off, deg, aggb, N);
    k_lin<4, true,  false, true,  false><<<gLin, 256, 0, stream>>>(aggb, hb, Wf2, b2_l, out, nullptr, N, TILES);
}